// Round 8
// baseline (217.098 us; speedup 1.0000x reference)
//
#include <hip/hip_runtime.h>

#define BATCH 65536

typedef __attribute__((ext_vector_type(8))) short bf16x8;
typedef __attribute__((ext_vector_type(4))) float f32x4;

__device__ __forceinline__ unsigned short f2bf(float f) {
  unsigned int u = __float_as_uint(f);
  u += 0x7fffu + ((u >> 16) & 1u);   // RNE (one-time weight builds only)
  return (unsigned short)(u >> 16);
}
// trunc-pack 2 floats -> 1 dword of 2 bf16 (lo in low half), single v_perm_b32
__device__ __forceinline__ unsigned pack_trunc(float lo, float hi) {
  return __builtin_amdgcn_perm(__float_as_uint(hi), __float_as_uint(lo), 0x07060302u);
}

// tanh(o)*sigmoid(u): 2 exp + 1 rcp; lower-bound clamps keep it NaN-proof.
__device__ __forceinline__ float gru_act(float u, float o) {
  u = fmaxf(u, -60.0f);
  o = fmaxf(o, -30.0f);
  float a  = __expf(-u);
  float a2 = __expf(-2.0f * o);
  return (1.0f - a2) * __builtin_amdgcn_rcpf((1.0f + a) * (1.0f + a2));
}

// LDS-only barrier: waits own DS ops (write visibility / read completion),
// does NOT drain vmcnt -> global prefetch loads stay in flight across it.
__device__ __forceinline__ void bar_lds() {
  asm volatile("s_waitcnt lgkmcnt(0)" ::: "memory");
  __builtin_amdgcn_sched_barrier(0);
  __builtin_amdgcn_s_barrier();
  __builtin_amdgcn_sched_barrier(0);
}

// conv 3x3 SAME on 3x3 grid, unrolled tap value
__device__ __forceinline__ float conv_tap(const float* __restrict__ w, int co, int ci,
                                          int p, int q, int CINTOT) {
  int pi = p / 3, pj = p % 3, qi = q / 3, qj = q % 3;
  int di = qi - pi + 1, dj = qj - pj + 1;
  if ((unsigned)di < 3u && (unsigned)dj < 3u)
    return w[((co * CINTOT + ci) * 3 + di) * 3 + dj];
  return 0.0f;
}

// BT[g][n][k] bf16, n = co*9+p, k = ci*9+q
__global__ void build_bt(const float* __restrict__ wu, const float* __restrict__ wo,
                         unsigned short* __restrict__ BT, int COUT, int CINX, int CINTOT) {
  int NG = COUT * 9, K = CINX * 9;
  int total = 2 * NG * K;
  int e = blockIdx.x * 256 + threadIdx.x;
  if (e >= total) return;
  int g = e / (NG * K);
  int rem = e - g * (NG * K);
  int n = rem / K, k = rem - n * K;
  BT[e] = f2bf(conv_tap(g ? wo : wu, n / 9, k / 9, n % 9, k % 9, CINTOT));
}

// A1 transposed: [g][q][c], c = col n in [0,288), q = input tap in [0,9)
__global__ void build_a1(const float* __restrict__ wu, const float* __restrict__ wo,
                         float* __restrict__ A1) {
  int e = blockIdx.x * 256 + threadIdx.x;
  if (e >= 5184) return;
  int g = e / 2592;
  int rem = e - g * 2592;
  int q = rem / 288, c = rem - q * 288;
  A1[e] = conv_tap(g ? wo : wu, c / 9, 0, c % 9, q, 33);
}

// ---------------- LDS layout (bytes), lifetimes barrier-separated ----------------
// [0,40960)   x1l (L1..L2) | x3l [0,18688) (L3 epi..dense) | wl [20480,25664)+blb
// [40960,90112)  Bl double-buffered: 2 x (384 rows x 64B)
// [90112,98304)  Al double-buffered: 2 x (64 rows x 64B)   (L3)
// [98304,101632) xl 64 x 13 f32 (L1 only)
#define OFF_X1L 0
#define OFF_X3L 0
#define OFF_WL 20480
#define OFF_BLB 25664
#define OFF_BL 40960
#define BL_STRIDE 24576
#define OFF_AL 90112
#define AL_STRIDE 4096
#define OFF_XL 98304
#define SMEM_BYTES 101632

__global__ __launch_bounds__(512, 2) void megafused(
    const float* __restrict__ xin, const float* __restrict__ A1,
    const float* __restrict__ b1u, const float* __restrict__ b1o,
    const unsigned short* __restrict__ BT2,
    const float* __restrict__ b2u, const float* __restrict__ b2o,
    const unsigned short* __restrict__ BT3,
    const float* __restrict__ b3u, const float* __restrict__ b3o,
    const float* __restrict__ wd, const float* __restrict__ bd,
    float* __restrict__ x1, float* __restrict__ x2,
    float* __restrict__ x3, float* __restrict__ out) {
  __shared__ __align__(16) char smem[SMEM_BYTES];
  char* x1l = smem + OFF_X1L;
  char* Bl = smem + OFF_BL;
  char* Al = smem + OFF_AL;
  unsigned short* x3l = (unsigned short*)(smem + OFF_X3L);
  float* xl = (float*)(smem + OFF_XL);
  float* wl = (float*)(smem + OFF_WL);
  float* blb = (float*)(smem + OFF_BLB);

  const int tid = threadIdx.x;
  const int lane = tid & 63;
  const int wid = tid >> 6;          // 0..7
  const int lrow = lane & 15;
  const int jc = (lane >> 4) & 3;
  const int mh = wid >> 2;           // row half
  const int cg = wid & 3;            // col group
  const int r0 = blockIdx.x * 64;
  const int srow = tid >> 2, spart = tid & 3;

  // L2 B-staging thread-constants: 3 chunks/thread, rows ci*128+srow in [0,384)
  unsigned toffB2[3];
  int wOffB2[3];
#pragma unroll
  for (int ci = 0; ci < 3; ++ci) {
    int row = ci * 128 + srow;
    int bg = (row < 192) ? row : (384 + row);   // BT2 row (gate1 at 576)
    toffB2[ci] = (unsigned)bg * 288u + spart * 8;
    wOffB2[ci] = row * 64 + ((spart ^ ((row >> 1) & 3)) << 4);
  }

  // stage x input (stride 13 floats: breaks the 4-way rq-group bank collision)
  for (int c = tid; c < 576; c += 512) xl[(c / 9) * 13 + (c % 9)] = xin[(size_t)r0 * 9 + c];
  __syncthreads();

  // issue L2 tile-0 B loads (in flight across all of L1)
  bf16x8 pf[3];
#pragma unroll
  for (int ci = 0; ci < 3; ++ci) pf[ci] = *(const bf16x8*)(BT2 + toffB2[ci]);

  // ---- L1: exact fp32. 1152 units = 288 cols x 4 row-quarters ----
  for (int uu = 0; uu < 3; ++uu) {
    int u = tid + (uu << 9);
    if (u < 1152) {
      int c = u >> 2, rq = u & 3;
      float au[9], ao[9];
#pragma unroll
      for (int q = 0; q < 9; ++q) {
        au[q] = A1[q * 288 + c];
        ao[q] = A1[2592 + q * 288 + c];
      }
      float bU = b1u[c / 9], bO = b1o[c / 9];
      const int cbase = c >> 3, cb = (c & 7) * 2;
#pragma unroll 4
      for (int i = 0; i < 16; ++i) {
        int r = (rq << 4) + i;
        const float4 xv0 = *(const float4*)&xl[r * 13];
        const float4 xv1 = *(const float4*)&xl[r * 13 + 4];
        const float x8 = xl[r * 13 + 8];
        float uacc = bU, oacc = bO;
        uacc = fmaf(au[0], xv0.x, uacc); oacc = fmaf(ao[0], xv0.x, oacc);
        uacc = fmaf(au[1], xv0.y, uacc); oacc = fmaf(ao[1], xv0.y, oacc);
        uacc = fmaf(au[2], xv0.z, uacc); oacc = fmaf(ao[2], xv0.z, oacc);
        uacc = fmaf(au[3], xv0.w, uacc); oacc = fmaf(ao[3], xv0.w, oacc);
        uacc = fmaf(au[4], xv1.x, uacc); oacc = fmaf(ao[4], xv1.x, oacc);
        uacc = fmaf(au[5], xv1.y, uacc); oacc = fmaf(ao[5], xv1.y, oacc);
        uacc = fmaf(au[6], xv1.z, uacc); oacc = fmaf(ao[6], xv1.z, oacc);
        uacc = fmaf(au[7], xv1.w, uacc); oacc = fmaf(ao[7], xv1.w, oacc);
        uacc = fmaf(au[8], x8, uacc);    oacc = fmaf(ao[8], x8, oacc);
        float v = gru_act(uacc, oacc);
        x1[(size_t)(r0 + r) * 288 + c] = v;
        *(unsigned short*)(x1l + r * 640 + ((cbase ^ (r & 7)) << 4) + cb) =
            (unsigned short)(__float_as_uint(v) >> 16);
      }
    }
  }

  // ---- L2: x1l(bf16) x BT2 -> x2 fp32. 27 steps, Bl dbuf, 1 raw barrier/step ----
  {
    int rBoff[2][3];
#pragma unroll
    for (int g = 0; g < 2; ++g)
#pragma unroll
      for (int f = 0; f < 3; ++f) {
        int rb = g * 192 + (cg * 3 + f) * 16 + lrow;
        rBoff[g][f] = rb * 64 + ((jc ^ ((rb >> 1) & 3)) << 4);
      }
    const char* aBase[2];
    int aXor[2];
#pragma unroll
    for (int m = 0; m < 2; ++m) {
      int row = mh * 32 + m * 16 + lrow;
      aBase[m] = x1l + row * 640;
      aXor[m] = row & 7;
    }

    // prologue: tile0 -> buf0 (waits on its loads); issue tile1; barrier
#pragma unroll
    for (int ci = 0; ci < 3; ++ci) *(bf16x8*)(Bl + wOffB2[ci]) = pf[ci];
#pragma unroll
    for (int ci = 0; ci < 3; ++ci) pf[ci] = *(const bf16x8*)(BT2 + 32u + toffB2[ci]);
    bar_lds();   // x1l + Bl(buf0) visible

    f32x4 acc[2][2][3] = {};
    for (int s = 0; s < 27; ++s) {
      const int kt = s - (s / 9) * 9;
      const int bsel = (s & 1) * BL_STRIDE;
      bf16x8 af[2];
      const int c8 = kt * 4 + jc;
#pragma unroll
      for (int m = 0; m < 2; ++m)
        af[m] = *(const bf16x8*)(aBase[m] + ((c8 ^ aXor[m]) << 4));
      bf16x8 bfr[2][3];
#pragma unroll
      for (int g = 0; g < 2; ++g)
#pragma unroll
        for (int f = 0; f < 3; ++f)
          bfr[g][f] = *(const bf16x8*)(Bl + bsel + rBoff[g][f]);
#pragma unroll
      for (int m = 0; m < 2; ++m)
#pragma unroll
        for (int g = 0; g < 2; ++g)
#pragma unroll
          for (int f = 0; f < 3; ++f)
            acc[m][g][f] = __builtin_amdgcn_mfma_f32_16x16x32_bf16(
                af[m], bfr[g][f], acc[m][g][f], 0, 0, 0);
      if (kt == 8) {
        const int n0 = (s / 9) * 192;
#pragma unroll
        for (int m = 0; m < 2; ++m)
#pragma unroll
          for (int f = 0; f < 3; ++f) {
            int n = n0 + (cg * 3 + f) * 16 + lrow;
            float bU = b2u[n / 9], bO = b2o[n / 9];
            f32x4 u = acc[m][0][f], o = acc[m][1][f];
#pragma unroll
            for (int t = 0; t < 4; ++t) {
              int r = r0 + mh * 32 + m * 16 + jc * 4 + t;
              x2[(size_t)r * 576 + n] = gru_act(u[t] + bU, o[t] + bO);
            }
            acc[m][0][f] = (f32x4){0.f, 0.f, 0.f, 0.f};
            acc[m][1][f] = (f32x4){0.f, 0.f, 0.f, 0.f};
          }
      }
      if (s < 26) {
        const int wsel = ((s + 1) & 1) * BL_STRIDE;
#pragma unroll
        for (int ci = 0; ci < 3; ++ci)
          *(bf16x8*)(Bl + wsel + wOffB2[ci]) = pf[ci];   // waits on tile s+1 loads
        if (s < 25) {
          int ns = s + 2;
          unsigned uoff = (unsigned)(ns / 9) * 55296u + (unsigned)(ns % 9) * 32u;
#pragma unroll
          for (int ci = 0; ci < 3; ++ci)
            pf[ci] = *(const bf16x8*)(BT2 + uoff + toffB2[ci]);
        }
        bar_lds();
      }
    }
  }
  __syncthreads();   // REAL barrier: drains x2 stores before L3 readback; x1l dead

  // ---- L3: x2 (L2-hot readback) x BT3 (N padded 144->192), dbuf Al+Bl ----
  {
    unsigned toffB3[3];
    int wOffB3[3];
    bool vB3[3];
#pragma unroll
    for (int ci = 0; ci < 3; ++ci) {
      int row = ci * 128 + srow;
      int g = row >= 192;
      int nloc = row - (g ? 192 : 0);
      vB3[ci] = (nloc < 144);
      toffB3[ci] = (unsigned)((g ? 144 : 0) + nloc) * 576u + spart * 8;
      wOffB3[ci] = row * 64 + ((spart ^ ((row >> 1) & 3)) << 4);
    }
    const float* pA = x2 + (size_t)(r0 + (tid >> 2)) * 576 + spart * 8;
    const int wAloff = (tid >> 2) * 64 + ((spart ^ (((tid >> 2) >> 1) & 3)) << 4);

    // issue tile-0 loads (covered by wl staging)
    float4 pa0 = {}, pa1 = {};
    if (tid < 256) {
      pa0 = *(const float4*)pA;
      pa1 = *(const float4*)(pA + 4);
    }
    bf16x8 pb[3];
#pragma unroll
    for (int ci = 0; ci < 3; ++ci)
      pb[ci] = vB3[ci] ? *(const bf16x8*)(BT3 + toffB3[ci])
                       : (bf16x8){0, 0, 0, 0, 0, 0, 0, 0};

    // stage dense weights (disjoint from x3l; visible by first bar_lds)
    for (int c = tid; c < 1296; c += 512) wl[c] = wd[c];
    if (tid < 9) blb[tid] = bd[tid];

    int rBoff3[2][3];
#pragma unroll
    for (int g = 0; g < 2; ++g)
#pragma unroll
      for (int f = 0; f < 3; ++f) {
        int rb = g * 192 + (cg * 3 + f) * 16 + lrow;
        rBoff3[g][f] = rb * 64 + ((jc ^ ((rb >> 1) & 3)) << 4);
      }
    int rAoff3[2];
#pragma unroll
    for (int m = 0; m < 2; ++m) {
      int row = mh * 32 + m * 16 + lrow;
      rAoff3[m] = row * 64 + ((jc ^ ((row >> 1) & 3)) << 4);
    }

    // prologue: tile0 -> buf0; issue tile1; barrier
    if (tid < 256) {
      uint4 h;
      h.x = pack_trunc(pa0.x, pa0.y);
      h.y = pack_trunc(pa0.z, pa0.w);
      h.z = pack_trunc(pa1.x, pa1.y);
      h.w = pack_trunc(pa1.z, pa1.w);
      *(uint4*)(Al + wAloff) = h;
    }
#pragma unroll
    for (int ci = 0; ci < 3; ++ci) *(bf16x8*)(Bl + wOffB3[ci]) = pb[ci];
    if (tid < 256) {
      pa0 = *(const float4*)(pA + 32);
      pa1 = *(const float4*)(pA + 36);
    }
#pragma unroll
    for (int ci = 0; ci < 3; ++ci)
      if (vB3[ci]) pb[ci] = *(const bf16x8*)(BT3 + 32u + toffB3[ci]);
    bar_lds();

    f32x4 acc[2][2][3] = {};
    for (int kt = 0; kt < 18; ++kt) {
      const int bsel = (kt & 1) * BL_STRIDE;
      const int asel = (kt & 1) * AL_STRIDE;
      bf16x8 af[2];
#pragma unroll
      for (int m = 0; m < 2; ++m) af[m] = *(const bf16x8*)(Al + asel + rAoff3[m]);
      bf16x8 bfr[2][3];
#pragma unroll
      for (int g = 0; g < 2; ++g)
#pragma unroll
        for (int f = 0; f < 3; ++f)
          bfr[g][f] = *(const bf16x8*)(Bl + bsel + rBoff3[g][f]);
#pragma unroll
      for (int m = 0; m < 2; ++m)
#pragma unroll
        for (int g = 0; g < 2; ++g)
#pragma unroll
          for (int f = 0; f < 3; ++f)
            acc[m][g][f] = __builtin_amdgcn_mfma_f32_16x16x32_bf16(
                af[m], bfr[g][f], acc[m][g][f], 0, 0, 0);
      if (kt < 17) {
        const int wbsel = ((kt + 1) & 1) * BL_STRIDE;
        const int wasel = ((kt + 1) & 1) * AL_STRIDE;
        if (tid < 256) {
          uint4 h;
          h.x = pack_trunc(pa0.x, pa0.y);
          h.y = pack_trunc(pa0.z, pa0.w);
          h.z = pack_trunc(pa1.x, pa1.y);
          h.w = pack_trunc(pa1.z, pa1.w);
          *(uint4*)(Al + wasel + wAloff) = h;
        }
#pragma unroll
        for (int ci = 0; ci < 3; ++ci)
          *(bf16x8*)(Bl + wbsel + wOffB3[ci]) = pb[ci];
        if (kt < 16) {
          if (tid < 256) {
            const float* gp = pA + (kt + 2) * 32;
            pa0 = *(const float4*)gp;
            pa1 = *(const float4*)(gp + 4);
          }
          unsigned uoff = (unsigned)(kt + 2) * 32u;
#pragma unroll
          for (int ci = 0; ci < 3; ++ci)
            if (vB3[ci]) pb[ci] = *(const bf16x8*)(BT3 + uoff + toffB3[ci]);
        }
        bar_lds();
      }
    }
    // epilogue: cg<3 carry real cols (n<144): act -> x3 global + x3l (trunc)
    if (cg < 3) {
#pragma unroll
      for (int m = 0; m < 2; ++m)
#pragma unroll
        for (int f = 0; f < 3; ++f) {
          int n = (cg * 3 + f) * 16 + lrow;
          float bU = b3u[n / 9], bO = b3o[n / 9];
          f32x4 u = acc[m][0][f], o = acc[m][1][f];
#pragma unroll
          for (int t = 0; t < 4; ++t) {
            int r = mh * 32 + m * 16 + jc * 4 + t;
            float v = gru_act(u[t] + bU, o[t] + bO);
            x3[(size_t)(r0 + r) * 144 + n] = v;
            x3l[r * 146 + n] = (unsigned short)(__float_as_uint(v) >> 16);
          }
        }
    }
  }
  __syncthreads();   // x3l ready

  // ---- dense head: 9 cols x 64 rows; wave j = col wid, plus wave0 col 8 ----
  {
    int row = lane;
    int j = wid;
    float s = blb[j];
    for (int k = 0; k < 144; k += 2) {
      unsigned pr = *(const unsigned*)&x3l[row * 146 + k];
      float v0 = __uint_as_float(pr << 16);
      float v1 = __uint_as_float(pr & 0xffff0000u);
      const float2 w0 = *(const float2*)&wl[j * 144 + k];
      s = fmaf(v0, w0.x, s);
      s = fmaf(v1, w0.y, s);
    }
    out[(size_t)(r0 + row) * 9 + j] = s;
    if (tid < 64) {
      float s8 = blb[8];
      for (int k = 0; k < 144; k += 2) {
        unsigned pr = *(const unsigned*)&x3l[row * 146 + k];
        float v0 = __uint_as_float(pr << 16);
        float v1 = __uint_as_float(pr & 0xffff0000u);
        const float2 w0 = *(const float2*)&wl[8 * 144 + k];
        s8 = fmaf(v0, w0.x, s8);
        s8 = fmaf(v1, w0.y, s8);
      }
      out[(size_t)(r0 + row) * 9 + 8] = s8;
    }
  }
}

extern "C" void kernel_launch(void* const* d_in, const int* in_sizes, int n_in,
                              void* d_out, int out_size, void* d_ws, size_t ws_size,
                              hipStream_t stream) {
  const float* inputs = (const float*)d_in[0];
  const float* wd  = (const float*)d_in[1];
  const float* bd  = (const float*)d_in[2];
  const float* w1u = (const float*)d_in[3];
  const float* b1u = (const float*)d_in[4];
  const float* w1o = (const float*)d_in[7];
  const float* b1o = (const float*)d_in[8];
  const float* w2u = (const float*)d_in[9];
  const float* b2u = (const float*)d_in[10];
  const float* w2o = (const float*)d_in[13];
  const float* b2o = (const float*)d_in[14];
  const float* w3u = (const float*)d_in[15];
  const float* b3u = (const float*)d_in[16];
  const float* w3o = (const float*)d_in[19];
  const float* b3o = (const float*)d_in[20];

  float* out = (float*)d_out;                    // [B][9]
  float* x1 = out + (size_t)BATCH * 9;           // [B][288]
  float* x2 = x1 + (size_t)BATCH * 288;          // [B][576]
  float* x3 = x2 + (size_t)BATCH * 576;          // [B][144]

  unsigned short* BT2 = (unsigned short*)d_ws;   // [2][576][288] bf16
  unsigned short* BT3 = BT2 + 331776;            // [2][144][576] bf16
  float* A1 = (float*)((char*)d_ws + 995328);    // [2][9][288] fp32

  build_bt<<<1296, 256, 0, stream>>>(w2u, w2o, BT2, 64, 32, 96);
  build_bt<<<648, 256, 0, stream>>>(w3u, w3o, BT3, 16, 64, 80);
  build_a1<<<21, 256, 0, stream>>>(w1u, w1o, A1);

  megafused<<<BATCH / 64, 512, 0, stream>>>(inputs, A1, b1u, b1o, BT2, b2u, b2o,
                                            BT3, b3u, b3o, wd, bd, x1, x2, x3, out);
}